// Round 6
// baseline (304.782 us; speedup 1.0000x reference)
//
#include <hip/hip_runtime.h>
#include <hip/hip_bf16.h>
#include <stdint.h>

// Problem constants
#define M_TOK 2048   // B*S
#define N_OUT 4096   // OUT_F
#define K_IN  4096   // IN_F
#define GROUPSZ 128
#define NGRP  32

typedef signed char i8;
typedef int    intx4  __attribute__((ext_vector_type(4)));
typedef float  floatx4 __attribute__((ext_vector_type(4)));

#define AS1 __attribute__((address_space(1)))
#define AS3 __attribute__((address_space(3)))

// ---------------- Kernel 1: fused quantization pass (one dispatch).
#define XQ_BLOCKS (M_TOK)                       // 2048, 256 thr = 1 row
#define WQ_BLOCKS (N_OUT * K_IN / 16 / 256)     // 4096

__global__ __launch_bounds__(256) void quant_kernel(
    const float* __restrict__ x, const int* __restrict__ wq,
    i8* __restrict__ xq, i8* __restrict__ wq8, float* __restrict__ sx) {
  __shared__ float red[4];
  int b = blockIdx.x;
  int tid = threadIdx.x;
  if (b < XQ_BLOCKS) {
    const float* xr = x + (size_t)b * K_IN;
    int e0 = tid * 16;
    float4 v0 = *(const float4*)(xr + e0);
    float4 v1 = *(const float4*)(xr + e0 + 4);
    float4 v2 = *(const float4*)(xr + e0 + 8);
    float4 v3 = *(const float4*)(xr + e0 + 12);
    float m = fabsf(v0.x);
    m = fmaxf(m, fabsf(v0.y)); m = fmaxf(m, fabsf(v0.z)); m = fmaxf(m, fabsf(v0.w));
    m = fmaxf(m, fabsf(v1.x)); m = fmaxf(m, fabsf(v1.y)); m = fmaxf(m, fabsf(v1.z)); m = fmaxf(m, fabsf(v1.w));
    m = fmaxf(m, fabsf(v2.x)); m = fmaxf(m, fabsf(v2.y)); m = fmaxf(m, fabsf(v2.z)); m = fmaxf(m, fabsf(v2.w));
    m = fmaxf(m, fabsf(v3.x)); m = fmaxf(m, fabsf(v3.y)); m = fmaxf(m, fabsf(v3.z)); m = fmaxf(m, fabsf(v3.w));
#pragma unroll
    for (int off = 32; off > 0; off >>= 1)
      m = fmaxf(m, __shfl_xor(m, off, 64));
    int lane = tid & 63, wv = tid >> 6;
    if (lane == 0) red[wv] = m;
    __syncthreads();
    m = fmaxf(fmaxf(red[0], red[1]), fmaxf(red[2], red[3]));
    float inv = (m > 0.f) ? 127.f / m : 0.f;
    union { i8 q[16]; int4 v; } u;
    u.q[0]  = (i8)(int)rintf(v0.x * inv); u.q[1]  = (i8)(int)rintf(v0.y * inv);
    u.q[2]  = (i8)(int)rintf(v0.z * inv); u.q[3]  = (i8)(int)rintf(v0.w * inv);
    u.q[4]  = (i8)(int)rintf(v1.x * inv); u.q[5]  = (i8)(int)rintf(v1.y * inv);
    u.q[6]  = (i8)(int)rintf(v1.z * inv); u.q[7]  = (i8)(int)rintf(v1.w * inv);
    u.q[8]  = (i8)(int)rintf(v2.x * inv); u.q[9]  = (i8)(int)rintf(v2.y * inv);
    u.q[10] = (i8)(int)rintf(v2.z * inv); u.q[11] = (i8)(int)rintf(v2.w * inv);
    u.q[12] = (i8)(int)rintf(v3.x * inv); u.q[13] = (i8)(int)rintf(v3.y * inv);
    u.q[14] = (i8)(int)rintf(v3.z * inv); u.q[15] = (i8)(int)rintf(v3.w * inv);
    *(int4*)(xq + (size_t)b * K_IN + e0) = u.v;
    if (tid == 0) sx[b] = m * (1.f / 127.f);
  } else {
    size_t t = (size_t)(b - XQ_BLOCKS) * 256 + tid;   // 1M threads
    size_t base = t * 16;
    const int* src = wq + base;
    int4 a0 = *(const int4*)(src);
    int4 a1 = *(const int4*)(src + 4);
    int4 a2 = *(const int4*)(src + 8);
    int4 a3 = *(const int4*)(src + 12);
    union { i8 q[16]; int4 v; } u;
    u.q[0]  = (i8)a0.x; u.q[1]  = (i8)a0.y; u.q[2]  = (i8)a0.z; u.q[3]  = (i8)a0.w;
    u.q[4]  = (i8)a1.x; u.q[5]  = (i8)a1.y; u.q[6]  = (i8)a1.z; u.q[7]  = (i8)a1.w;
    u.q[8]  = (i8)a2.x; u.q[9]  = (i8)a2.y; u.q[10] = (i8)a2.z; u.q[11] = (i8)a2.w;
    u.q[12] = (i8)a3.x; u.q[13] = (i8)a3.y; u.q[14] = (i8)a3.z; u.q[15] = (i8)a3.w;
    *(int4*)(wq8 + base) = u.v;
  }
}

// ---------------- Kernel 2: int8 GEMM with per-group fp32 rescale + bias.
// y[n,o] = s_x[n] * sum_g( s_w[g,o] * dot_i32(xq[n,g,:], w[o,g,:]) ) + bias[o]
//
// R13. Evidence across R7-R12: performance tracks co-resident independent
// barrier domains (R7's 2-3 blocks/CU = 52us beat every 8-wave/1-block
// pipelined variant at 57-84us); intra-block phase overlap never
// materialized at 1-2 waves/SIMD. So: maximize residency and keep the
// three verified ratio wins.
//  - BM=BN=128, 256 thr = 4 waves of 64x64 (R11's verified inner loop).
//    SINGLE-buffered LDS = As 16K + Bs 16K = 32KB exactly. sws in reg
//    prefetch, sx at epilogue. With ~100 VGPR: occupancy = min(160/32,
//    512/100) = 5 blocks/CU target, 16-20 waves/CU (R7-level TLP) with
//    DS/MAC -33% vs R7, 0 bank conflicts, no v_cvt rescale tax.
//  - R7-style drain loop: sync; stage(t); sync(vmcnt0+lgkm0 drain);
//    compute. Cross-block phase shift hides the drains.
//  - Verified pieces: 128B-row 3-bit XOR swizzle (R11: 0 conflicts),
//    magic-bias rescale (C-init 0x4B400000; bitcast-12582912.0f exact for
//    |dot| <= 113792 << 2^22), mfma_i32_16x16x64_i8.
#define BM 128
#define BN 128
#define BK 128
#define NT (K_IN / BK)   // 32

__global__ __launch_bounds__(256, 4) void gemm_i8_kernel(
    const i8* __restrict__ Aq, const i8* __restrict__ Bq,
    const float* __restrict__ sx, const float* __restrict__ sw,
    const float* __restrict__ bias, float* __restrict__ C) {
  __shared__ i8 As[BM * BK];            // 16 KB (single-buffered)
  __shared__ i8 Bs[BN * BK];            // 16 KB (single-buffered)

  const int tid  = threadIdx.x;
  const int lane = tid & 63;
  const int wave = tid >> 6;       // 0..3
  const int quad = lane >> 4;      // 0..3
  const int l16  = lane & 15;
  const int bm = blockIdx.y;
  const int bn = blockIdx.x;
  const int wm = wave >> 1;        // 0..1 -> 64-row slab of 128
  const int wn = wave & 1;         // 0..1 -> 64-col slab of 128

  const int rowA0 = bm * BM;
  const int rowB0 = bn * BN;

  // Hoisted staging sources: 1024 16B-chunks per matrix, 4 per thread.
  // Global source chunk-col pre-swizzled (involution c ^= row&7); LDS dest
  // linear (global_load_lds constraint); reads apply the same XOR.
  const i8* srcA[4]; const i8* srcB[4];
#pragma unroll
  for (int i = 0; i < 4; ++i) {
    int chunk = i * 256 + tid;              // 0..1023
    int row = chunk >> 3;                   // 0..127
    int csw = (chunk & 7) ^ (row & 7);
    srcA[i] = Aq + (size_t)(rowA0 + row) * K_IN + (csw << 4);
    srcB[i] = Bq + (size_t)(rowB0 + row) * K_IN + (csw << 4);
  }
  // Wave-uniform LDS dests (HW adds lane*16).
  i8* dstA[4]; i8* dstB[4];
#pragma unroll
  for (int i = 0; i < 4; ++i) {
    dstA[i] = As + (size_t)(i * 256 + wave * 64) * 16;
    dstB[i] = Bs + (size_t)(i * 256 + wave * 64) * 16;
  }

  // s_w pointer for this wave's 4 column frags.
  const float* swp = sw + rowB0 + wn * 64 + l16;

  floatx4 master[4][4];
#pragma unroll
  for (int i = 0; i < 4; ++i)
#pragma unroll
    for (int j = 0; j < 4; ++j) master[i][j] = (floatx4)0.0f;

  const intx4 MAGICV = {0x4B400000, 0x4B400000, 0x4B400000, 0x4B400000};
  const float MAGICF = 12582912.0f;        // 1.5 * 2^23

  const int h  = l16 & 7;
  const int x0 = (quad ^ h) << 4;          // swizzled byte offset, k-half 0
  const int x1 = x0 ^ 64;                  // k-half 1 (chunk ^ 4)

  for (int t = 0; t < NT; ++t) {
    __syncthreads();   // previous compute's ds_reads done (lgkm drained)
    {
      const size_t ko = (size_t)t * BK;
#pragma unroll
      for (int i = 0; i < 4; ++i)
        __builtin_amdgcn_global_load_lds(
            (const AS1 void*)(srcA[i] + ko), (AS3 void*)dstA[i], 16, 0, 0);
#pragma unroll
      for (int i = 0; i < 4; ++i)
        __builtin_amdgcn_global_load_lds(
            (const AS1 void*)(srcB[i] + ko), (AS3 void*)dstB[i], 16, 0, 0);
    }
    float swv[4];
#pragma unroll
    for (int j = 0; j < 4; ++j)            // 4 dword loads (L2-hot)
      swv[j] = swp[(size_t)t * N_OUT + j * 16];
    __syncthreads();   // vmcnt(0)+lgkmcnt(0) drain: tile t + swv landed

    intx4 a[4][2], b[4][2];
#pragma unroll
    for (int i = 0; i < 4; ++i) {
      const i8* pa = As + (size_t)(wm * 64 + i * 16 + l16) * BK;
      a[i][0] = *(const intx4*)(pa + x0);
      a[i][1] = *(const intx4*)(pa + x1);
    }
#pragma unroll
    for (int j = 0; j < 4; ++j) {
      const i8* pb = Bs + (size_t)(wn * 64 + j * 16 + l16) * BK;
      b[j][0] = *(const intx4*)(pb + x0);
      b[j][1] = *(const intx4*)(pb + x1);
    }

    // 16 frag-chains: 2 dependent MFMAs each (K=128 = one quant group),
    // magic-seeded so int->float is a free bitcast; compiler interleaves
    // ds_reads and MFMAs with fine-grained lgkmcnt.
#pragma unroll
    for (int i = 0; i < 4; ++i)
#pragma unroll
      for (int j = 0; j < 4; ++j) {
        intx4 acc = __builtin_amdgcn_mfma_i32_16x16x64_i8(a[i][0], b[j][0], MAGICV, 0, 0, 0);
        acc = __builtin_amdgcn_mfma_i32_16x16x64_i8(a[i][1], b[j][1], acc, 0, 0, 0);
        master[i][j] += (__builtin_bit_cast(floatx4, acc) - MAGICF) * swv[j];
      }
  }

  // Epilogue: C/D layout col = lane&15 (n), row = quad*4 + reg (m).
  // y = master * s_x[row] + bias[col]. sx/bias from global (L2-hot).
#pragma unroll
  for (int i = 0; i < 4; ++i) {
    float4 sxv = *(const float4*)(sx + rowA0 + wm * 64 + i * 16 + quad * 4);
#pragma unroll
    for (int j = 0; j < 4; ++j) {
      int col = rowB0 + wn * 64 + j * 16 + l16;
      float bv = bias[col];
      int rloc = wm * 64 + i * 16 + quad * 4;
      C[(size_t)(rowA0 + rloc + 0) * N_OUT + col] = master[i][j][0] * sxv.x + bv;
      C[(size_t)(rowA0 + rloc + 1) * N_OUT + col] = master[i][j][1] * sxv.y + bv;
      C[(size_t)(rowA0 + rloc + 2) * N_OUT + col] = master[i][j][2] * sxv.z + bv;
      C[(size_t)(rowA0 + rloc + 3) * N_OUT + col] = master[i][j][3] * sxv.w + bv;
    }
  }
}

extern "C" void kernel_launch(void* const* d_in, const int* in_sizes, int n_in,
                              void* d_out, int out_size, void* d_ws, size_t ws_size,
                              hipStream_t stream) {
  const float* x    = (const float*)d_in[0];
  const int*   wq   = (const int*)d_in[1];     // integer input -> int32 per harness
  const float* sw   = (const float*)d_in[2];
  const float* bias = (const float*)d_in[3];
  float* out = (float*)d_out;

  i8*    xq  = (i8*)d_ws;                                          // 8 MB
  i8*    wq8 = (i8*)((char*)d_ws + (size_t)M_TOK * K_IN);          // 16 MB
  float* sx  = (float*)((char*)d_ws + (size_t)M_TOK * K_IN
                                     + (size_t)N_OUT * K_IN);      // 8 KB

  {
    int nblocks = XQ_BLOCKS + WQ_BLOCKS;        // 6144
    quant_kernel<<<nblocks, 256, 0, stream>>>(x, wq, xq, wq8, sx);
  }
  {
    dim3 grid(N_OUT / BN, M_TOK / BM);          // (32, 16) = 512 blocks
    gemm_i8_kernel<<<grid, 256, 0, stream>>>(xq, wq8, sx, sw, bias, out);
  }
}

// Round 7
// 239.745 us; speedup vs baseline: 1.2713x; 1.2713x over previous
//
#include <hip/hip_runtime.h>
#include <hip/hip_bf16.h>
#include <stdint.h>

// Problem constants
#define M_TOK 2048   // B*S
#define N_OUT 4096   // OUT_F
#define K_IN  4096   // IN_F
#define GROUPSZ 128
#define NGRP  32

typedef signed char i8;
typedef int    intx4  __attribute__((ext_vector_type(4)));
typedef float  floatx4 __attribute__((ext_vector_type(4)));

#define AS1 __attribute__((address_space(1)))
#define AS3 __attribute__((address_space(3)))

// ---------------- Kernel 1: fused quantization pass (one dispatch).
#define XQ_BLOCKS (M_TOK)                       // 2048, 256 thr = 1 row
#define WQ_BLOCKS (N_OUT * K_IN / 16 / 256)     // 4096

__global__ __launch_bounds__(256) void quant_kernel(
    const float* __restrict__ x, const int* __restrict__ wq,
    i8* __restrict__ xq, i8* __restrict__ wq8, float* __restrict__ sx) {
  __shared__ float red[4];
  int b = blockIdx.x;
  int tid = threadIdx.x;
  if (b < XQ_BLOCKS) {
    const float* xr = x + (size_t)b * K_IN;
    int e0 = tid * 16;
    float4 v0 = *(const float4*)(xr + e0);
    float4 v1 = *(const float4*)(xr + e0 + 4);
    float4 v2 = *(const float4*)(xr + e0 + 8);
    float4 v3 = *(const float4*)(xr + e0 + 12);
    float m = fabsf(v0.x);
    m = fmaxf(m, fabsf(v0.y)); m = fmaxf(m, fabsf(v0.z)); m = fmaxf(m, fabsf(v0.w));
    m = fmaxf(m, fabsf(v1.x)); m = fmaxf(m, fabsf(v1.y)); m = fmaxf(m, fabsf(v1.z)); m = fmaxf(m, fabsf(v1.w));
    m = fmaxf(m, fabsf(v2.x)); m = fmaxf(m, fabsf(v2.y)); m = fmaxf(m, fabsf(v2.z)); m = fmaxf(m, fabsf(v2.w));
    m = fmaxf(m, fabsf(v3.x)); m = fmaxf(m, fabsf(v3.y)); m = fmaxf(m, fabsf(v3.z)); m = fmaxf(m, fabsf(v3.w));
#pragma unroll
    for (int off = 32; off > 0; off >>= 1)
      m = fmaxf(m, __shfl_xor(m, off, 64));
    int lane = tid & 63, wv = tid >> 6;
    if (lane == 0) red[wv] = m;
    __syncthreads();
    m = fmaxf(fmaxf(red[0], red[1]), fmaxf(red[2], red[3]));
    float inv = (m > 0.f) ? 127.f / m : 0.f;
    union { i8 q[16]; int4 v; } u;
    u.q[0]  = (i8)(int)rintf(v0.x * inv); u.q[1]  = (i8)(int)rintf(v0.y * inv);
    u.q[2]  = (i8)(int)rintf(v0.z * inv); u.q[3]  = (i8)(int)rintf(v0.w * inv);
    u.q[4]  = (i8)(int)rintf(v1.x * inv); u.q[5]  = (i8)(int)rintf(v1.y * inv);
    u.q[6]  = (i8)(int)rintf(v1.z * inv); u.q[7]  = (i8)(int)rintf(v1.w * inv);
    u.q[8]  = (i8)(int)rintf(v2.x * inv); u.q[9]  = (i8)(int)rintf(v2.y * inv);
    u.q[10] = (i8)(int)rintf(v2.z * inv); u.q[11] = (i8)(int)rintf(v2.w * inv);
    u.q[12] = (i8)(int)rintf(v3.x * inv); u.q[13] = (i8)(int)rintf(v3.y * inv);
    u.q[14] = (i8)(int)rintf(v3.z * inv); u.q[15] = (i8)(int)rintf(v3.w * inv);
    *(int4*)(xq + (size_t)b * K_IN + e0) = u.v;
    if (tid == 0) sx[b] = m * (1.f / 127.f);
  } else {
    size_t t = (size_t)(b - XQ_BLOCKS) * 256 + tid;   // 1M threads
    size_t base = t * 16;
    const int* src = wq + base;
    int4 a0 = *(const int4*)(src);
    int4 a1 = *(const int4*)(src + 4);
    int4 a2 = *(const int4*)(src + 8);
    int4 a3 = *(const int4*)(src + 12);
    union { i8 q[16]; int4 v; } u;
    u.q[0]  = (i8)a0.x; u.q[1]  = (i8)a0.y; u.q[2]  = (i8)a0.z; u.q[3]  = (i8)a0.w;
    u.q[4]  = (i8)a1.x; u.q[5]  = (i8)a1.y; u.q[6]  = (i8)a1.z; u.q[7]  = (i8)a1.w;
    u.q[8]  = (i8)a2.x; u.q[9]  = (i8)a2.y; u.q[10] = (i8)a2.z; u.q[11] = (i8)a2.w;
    u.q[12] = (i8)a3.x; u.q[13] = (i8)a3.y; u.q[14] = (i8)a3.z; u.q[15] = (i8)a3.w;
    *(int4*)(wq8 + base) = u.v;
  }
}

// ---------------- Kernel 2: int8 GEMM with per-group fp32 rescale + bias.
// y[n,o] = s_x[n] * sum_g( s_w[g,o] * dot_i32(xq[n,g,:], w[o,g,:]) ) + bias[o]
//
// R14. Key insight from R13's counters: grid = 512 blocks on 256 CUs caps
// residency at 2 blocks/CU NO MATTER the resources — R7's edge was simply
// 2 blocks x 8 waves = 16 waves/CU. And launch_bounds(_,4) caused a spill
// (VGPR 64, WRITE_SIZE 312MB scratch). R14 gets 16 waves/CU AND keeps the
// 64x64-wave DS ratio via in-block K-split:
//  - BM=BN=128, 512 thr = 8 waves: 4 output tiles of 64x64, 2 waves per
//    tile split along K (kgrp = wave&1 computes k-half kgrp of each
//    K=128 group: 1 MFMA/frag, 8 ds_reads/tile/wave). Block totals equal
//    R11 (64 reads, 128 MFMA) spread over 8 waves -> 4 waves/SIMD.
//  - Half-dot magic-bias still exact: |dot| <= 64*127*7 = 56896 << 2^22.
//  - Pair reduction at epilogue: 2-round XOR-swizzled exchange through Bs
//    (32KB), each wave then owns+stores 32 rows of its tile.
//  - R11-verbatim pipeline: double-buffer, counted vmcnt(8) (4 stage + 4
//    swv in flight), end-of-iter lgkm(0)+barrier, 0-conflict swizzle.
#define BM 128
#define BN 128
#define BK 128
#define NT (K_IN / BK)   // 32
#define BUFSZ (BM * BK)  // 16384

__global__ __launch_bounds__(512, 2) void gemm_i8_kernel(
    const i8* __restrict__ Aq, const i8* __restrict__ Bq,
    const float* __restrict__ sx, const float* __restrict__ sw,
    const float* __restrict__ bias, float* __restrict__ C) {
  __shared__ i8 As[2 * BUFSZ];          // 32 KB (double-buffered)
  __shared__ i8 Bs[2 * BUFSZ];          // 32 KB (double-buffered; reused
                                        //        as 32KB exchange buffer)
  const int tid  = threadIdx.x;
  const int lane = tid & 63;
  const int wave = tid >> 6;       // 0..7
  const int quad = lane >> 4;      // 0..3
  const int l16  = lane & 15;
  const int ot   = wave >> 1;      // 0..3: output 64x64 tile
  const int kgrp = wave & 1;       // 0..1: K-half of each group
  const int wm   = ot >> 1;        // 0..1 -> 64-row slab
  const int wn   = ot & 1;         // 0..1 -> 64-col slab
  const int bm = blockIdx.y;
  const int bn = blockIdx.x;

  const int rowA0 = bm * BM;
  const int rowB0 = bn * BN;

  // Staging: 1024 16B-chunks per matrix, 2 per thread (512 thr).
  // Global chunk-col pre-swizzled (involution c ^= row&7); LDS linear.
  const i8* srcA[2]; const i8* srcB[2];
  i8* dstA[2]; i8* dstB[2];
#pragma unroll
  for (int i = 0; i < 2; ++i) {
    int chunk = i * 512 + tid;              // 0..1023
    int row = chunk >> 3;                   // 0..127
    int csw = (chunk & 7) ^ (row & 7);
    srcA[i] = Aq + (size_t)(rowA0 + row) * K_IN + (csw << 4);
    srcB[i] = Bq + (size_t)(rowB0 + row) * K_IN + (csw << 4);
    dstA[i] = As + (size_t)(i * 512 + wave * 64) * 16;
    dstB[i] = Bs + (size_t)(i * 512 + wave * 64) * 16;
  }

  auto stage = [&](int buf, int t) {        // 4 global_load_lds / thread
    const size_t ko = (size_t)t * BK;
#pragma unroll
    for (int i = 0; i < 2; ++i)
      __builtin_amdgcn_global_load_lds(
          (const AS1 void*)(srcA[i] + ko),
          (AS3 void*)(dstA[i] + (size_t)buf * BUFSZ), 16, 0, 0);
#pragma unroll
    for (int i = 0; i < 2; ++i)
      __builtin_amdgcn_global_load_lds(
          (const AS1 void*)(srcB[i] + ko),
          (AS3 void*)(dstB[i] + (size_t)buf * BUFSZ), 16, 0, 0);
  };

  // s_w pointer for this wave's 4 column frags.
  const float* swp = sw + rowB0 + wn * 64 + l16;

  // Prologue: tile-0 stage + s_w(0) prefetch; one-time full drain.
  stage(0, 0);
  float swv_cur[4], swv_nxt[4];
#pragma unroll
  for (int j = 0; j < 4; ++j) swv_cur[j] = swp[j * 16];
  __syncthreads();

  floatx4 master[4][4];
#pragma unroll
  for (int i = 0; i < 4; ++i)
#pragma unroll
    for (int j = 0; j < 4; ++j) master[i][j] = (floatx4)0.0f;

  const intx4 MAGICV = {0x4B400000, 0x4B400000, 0x4B400000, 0x4B400000};
  const float MAGICF = 12582912.0f;        // 1.5 * 2^23

  // This wave's k-half chunk: global chunk (4*kgrp + quad), swizzled by l16&7.
  const int xk = (((quad ^ (l16 & 7)) ^ (kgrp << 2)) << 4);

  for (int t = 0; t < NT; ++t) {
    const int cur = t & 1;
    if (t + 1 < NT) {
      stage(cur ^ 1, t + 1);               // 4 loads in flight
#pragma unroll
      for (int j = 0; j < 4; ++j)          // +4 swv loads (L2-hot)
        swv_nxt[j] = swp[(size_t)(t + 1) * N_OUT + j * 16];
      asm volatile("s_waitcnt vmcnt(8)" ::: "memory");   // tile t landed
    } else {
      asm volatile("s_waitcnt vmcnt(0)" ::: "memory");   // final tile
    }
    __builtin_amdgcn_s_barrier();          // BARRIER_A: cur readable

    const i8* Ab = As + (size_t)cur * BUFSZ;
    const i8* Bb = Bs + (size_t)cur * BUFSZ;
    intx4 a[4], b[4];
#pragma unroll
    for (int i = 0; i < 4; ++i)
      a[i] = *(const intx4*)(Ab + (size_t)(wm * 64 + i * 16 + l16) * BK + xk);
#pragma unroll
    for (int j = 0; j < 4; ++j)
      b[j] = *(const intx4*)(Bb + (size_t)(wn * 64 + j * 16 + l16) * BK + xk);

    // 16 independent MFMAs (this wave's K=64 half of the group),
    // magic-seeded so int->float is a free bitcast; rescale by s_w[g,col]
    // applies linearly to half-group partials.
#pragma unroll
    for (int i = 0; i < 4; ++i)
#pragma unroll
      for (int j = 0; j < 4; ++j) {
        intx4 acc = __builtin_amdgcn_mfma_i32_16x16x64_i8(a[i], b[j], MAGICV, 0, 0, 0);
        master[i][j] += (__builtin_bit_cast(floatx4, acc) - MAGICF) * swv_cur[j];
      }
#pragma unroll
    for (int j = 0; j < 4; ++j) swv_cur[j] = swv_nxt[j];

    asm volatile("s_waitcnt lgkmcnt(0)" ::: "memory");
    __builtin_amdgcn_s_barrier();          // BARRIER_B: other buf writable
  }

  // ---- K-split pair reduction via Bs (32KB), 2 rounds, XOR-swizzled.
  // Round 0: kgrp1 writes master[0..1][*]; kgrp0 adds -> owns rows 0..31.
  // Round 1: kgrp0 writes master[2..3][*]; kgrp1 adds -> owns rows 32..63.
  floatx4* xb = (floatx4*)Bs;
  const int xbase = (ot * 64 + lane) * 8;
  if (kgrp == 1) {
#pragma unroll
    for (int ii = 0; ii < 2; ++ii)
#pragma unroll
      for (int j = 0; j < 4; ++j) {
        int c = ii * 4 + j;
        xb[xbase + (c ^ (lane & 7))] = master[ii][j];
      }
  }
  __syncthreads();
  if (kgrp == 0) {
#pragma unroll
    for (int ii = 0; ii < 2; ++ii)
#pragma unroll
      for (int j = 0; j < 4; ++j) {
        int c = ii * 4 + j;
        master[ii][j] += xb[xbase + (c ^ (lane & 7))];
      }
  }
  __syncthreads();
  if (kgrp == 0) {
#pragma unroll
    for (int ii = 2; ii < 4; ++ii)
#pragma unroll
      for (int j = 0; j < 4; ++j) {
        int c = (ii - 2) * 4 + j;
        xb[xbase + (c ^ (lane & 7))] = master[ii][j];
      }
  }
  __syncthreads();
  if (kgrp == 1) {
#pragma unroll
    for (int ii = 2; ii < 4; ++ii)
#pragma unroll
      for (int j = 0; j < 4; ++j) {
        int c = (ii - 2) * 4 + j;
        master[ii][j] += xb[xbase + (c ^ (lane & 7))];
      }
  }

  // Epilogue: each wave stores its owned 32-row half (ii = 2*kgrp..+1).
  // C/D layout col = lane&15 (n), row = quad*4 + reg (m).
  const int i0 = kgrp * 2;
#pragma unroll
  for (int ii = 0; ii < 2; ++ii) {
    int i = i0 + ii;
    float4 sxv = *(const float4*)(sx + rowA0 + wm * 64 + i * 16 + quad * 4);
#pragma unroll
    for (int j = 0; j < 4; ++j) {
      int col = rowB0 + wn * 64 + j * 16 + l16;
      float bv = bias[col];
      int rloc = wm * 64 + i * 16 + quad * 4;
      C[(size_t)(rowA0 + rloc + 0) * N_OUT + col] = master[i][j][0] * sxv.x + bv;
      C[(size_t)(rowA0 + rloc + 1) * N_OUT + col] = master[i][j][1] * sxv.y + bv;
      C[(size_t)(rowA0 + rloc + 2) * N_OUT + col] = master[i][j][2] * sxv.z + bv;
      C[(size_t)(rowA0 + rloc + 3) * N_OUT + col] = master[i][j][3] * sxv.w + bv;
    }
  }
}

extern "C" void kernel_launch(void* const* d_in, const int* in_sizes, int n_in,
                              void* d_out, int out_size, void* d_ws, size_t ws_size,
                              hipStream_t stream) {
  const float* x    = (const float*)d_in[0];
  const int*   wq   = (const int*)d_in[1];     // integer input -> int32 per harness
  const float* sw   = (const float*)d_in[2];
  const float* bias = (const float*)d_in[3];
  float* out = (float*)d_out;

  i8*    xq  = (i8*)d_ws;                                          // 8 MB
  i8*    wq8 = (i8*)((char*)d_ws + (size_t)M_TOK * K_IN);          // 16 MB
  float* sx  = (float*)((char*)d_ws + (size_t)M_TOK * K_IN
                                     + (size_t)N_OUT * K_IN);      // 8 KB

  {
    int nblocks = XQ_BLOCKS + WQ_BLOCKS;        // 6144
    quant_kernel<<<nblocks, 256, 0, stream>>>(x, wq, xq, wq8, sx);
  }
  {
    dim3 grid(N_OUT / BN, M_TOK / BM);          // (32, 16) = 512 blocks
    gemm_i8_kernel<<<grid, 512, 0, stream>>>(xq, wq8, sx, sw, bias, out);
  }
}

// Round 8
// 204.815 us; speedup vs baseline: 1.4881x; 1.1705x over previous
//
#include <hip/hip_runtime.h>
#include <hip/hip_bf16.h>
#include <stdint.h>

// Problem constants
#define M_TOK 2048   // B*S
#define N_OUT 4096   // OUT_F
#define K_IN  4096   // IN_F
#define GROUPSZ 128
#define NGRP  32

typedef signed char i8;
typedef int    intx4  __attribute__((ext_vector_type(4)));
typedef float  floatx4 __attribute__((ext_vector_type(4)));

#define AS1 __attribute__((address_space(1)))
#define AS3 __attribute__((address_space(3)))

// ---------------- Kernel 1: fused quantization pass (one dispatch).
#define XQ_BLOCKS (M_TOK)                       // 2048, 256 thr = 1 row
#define WQ_BLOCKS (N_OUT * K_IN / 16 / 256)     // 4096

__global__ __launch_bounds__(256) void quant_kernel(
    const float* __restrict__ x, const int* __restrict__ wq,
    i8* __restrict__ xq, i8* __restrict__ wq8, float* __restrict__ sx) {
  __shared__ float red[4];
  int b = blockIdx.x;
  int tid = threadIdx.x;
  if (b < XQ_BLOCKS) {
    const float* xr = x + (size_t)b * K_IN;
    int e0 = tid * 16;
    float4 v0 = *(const float4*)(xr + e0);
    float4 v1 = *(const float4*)(xr + e0 + 4);
    float4 v2 = *(const float4*)(xr + e0 + 8);
    float4 v3 = *(const float4*)(xr + e0 + 12);
    float m = fabsf(v0.x);
    m = fmaxf(m, fabsf(v0.y)); m = fmaxf(m, fabsf(v0.z)); m = fmaxf(m, fabsf(v0.w));
    m = fmaxf(m, fabsf(v1.x)); m = fmaxf(m, fabsf(v1.y)); m = fmaxf(m, fabsf(v1.z)); m = fmaxf(m, fabsf(v1.w));
    m = fmaxf(m, fabsf(v2.x)); m = fmaxf(m, fabsf(v2.y)); m = fmaxf(m, fabsf(v2.z)); m = fmaxf(m, fabsf(v2.w));
    m = fmaxf(m, fabsf(v3.x)); m = fmaxf(m, fabsf(v3.y)); m = fmaxf(m, fabsf(v3.z)); m = fmaxf(m, fabsf(v3.w));
#pragma unroll
    for (int off = 32; off > 0; off >>= 1)
      m = fmaxf(m, __shfl_xor(m, off, 64));
    int lane = tid & 63, wv = tid >> 6;
    if (lane == 0) red[wv] = m;
    __syncthreads();
    m = fmaxf(fmaxf(red[0], red[1]), fmaxf(red[2], red[3]));
    float inv = (m > 0.f) ? 127.f / m : 0.f;
    union { i8 q[16]; int4 v; } u;
    u.q[0]  = (i8)(int)rintf(v0.x * inv); u.q[1]  = (i8)(int)rintf(v0.y * inv);
    u.q[2]  = (i8)(int)rintf(v0.z * inv); u.q[3]  = (i8)(int)rintf(v0.w * inv);
    u.q[4]  = (i8)(int)rintf(v1.x * inv); u.q[5]  = (i8)(int)rintf(v1.y * inv);
    u.q[6]  = (i8)(int)rintf(v1.z * inv); u.q[7]  = (i8)(int)rintf(v1.w * inv);
    u.q[8]  = (i8)(int)rintf(v2.x * inv); u.q[9]  = (i8)(int)rintf(v2.y * inv);
    u.q[10] = (i8)(int)rintf(v2.z * inv); u.q[11] = (i8)(int)rintf(v2.w * inv);
    u.q[12] = (i8)(int)rintf(v3.x * inv); u.q[13] = (i8)(int)rintf(v3.y * inv);
    u.q[14] = (i8)(int)rintf(v3.z * inv); u.q[15] = (i8)(int)rintf(v3.w * inv);
    *(int4*)(xq + (size_t)b * K_IN + e0) = u.v;
    if (tid == 0) sx[b] = m * (1.f / 127.f);
  } else {
    size_t t = (size_t)(b - XQ_BLOCKS) * 256 + tid;   // 1M threads
    size_t base = t * 16;
    const int* src = wq + base;
    int4 a0 = *(const int4*)(src);
    int4 a1 = *(const int4*)(src + 4);
    int4 a2 = *(const int4*)(src + 8);
    int4 a3 = *(const int4*)(src + 12);
    union { i8 q[16]; int4 v; } u;
    u.q[0]  = (i8)a0.x; u.q[1]  = (i8)a0.y; u.q[2]  = (i8)a0.z; u.q[3]  = (i8)a0.w;
    u.q[4]  = (i8)a1.x; u.q[5]  = (i8)a1.y; u.q[6]  = (i8)a1.z; u.q[7]  = (i8)a1.w;
    u.q[8]  = (i8)a2.x; u.q[9]  = (i8)a2.y; u.q[10] = (i8)a2.z; u.q[11] = (i8)a2.w;
    u.q[12] = (i8)a3.x; u.q[13] = (i8)a3.y; u.q[14] = (i8)a3.z; u.q[15] = (i8)a3.w;
    *(int4*)(wq8 + base) = u.v;
  }
}

// ---------------- Kernel 2: int8 GEMM with per-group fp32 rescale + bias.
// y[n,o] = s_x[n] * sum_g( s_w[g,o] * dot_i32(xq[n,g,:], w[o,g,:]) ) + bias[o]
//
// R15 = R14 with the rule-#20 violation fixed. R14's counters (VGPR 76,
// WRITE_SIZE 189MB, FETCH 64MB, MfmaUtil 12%) showed the master[4][4]
// accumulator spilled to scratch because the epilogue indexed it with
// runtime i0 = kgrp*2. Everything is now compile-time-indexed (literal
// loop bounds + static wave-uniform branches). Also: s_w loads issue at
// the TOP of each iter (before stage) so they are the OLDEST outstanding
// VMEM ops -> compiler's auto-wait before the rescale is vmcnt(4), and
// stage(t+1) stays in flight (never drain to 0 in-loop).
//
// Structure (R14): BM=BN=128, 512 thr = 8 waves: 4 output tiles of 64x64,
// 2 waves per tile split along K (kgrp computes its K=64 half-group:
// 1 MFMA/frag, 8 ds_reads/tile/wave). Block totals equal R11 (64 reads,
// 128 MFMA) spread over 8 waves; grid-capped 2 blocks/CU -> 16 waves/CU.
// Half-dot magic-bias exact: |dot| <= 64*127*7 = 56896 << 2^22.
// Pair reduction at epilogue via 2-round XOR-swizzled exchange through Bs.
// Verified: 128B-row 3-bit XOR swizzle (0 main-loop conflicts).
#define BM 128
#define BN 128
#define BK 128
#define NT (K_IN / BK)   // 32
#define BUFSZ (BM * BK)  // 16384

__global__ __launch_bounds__(512, 2) void gemm_i8_kernel(
    const i8* __restrict__ Aq, const i8* __restrict__ Bq,
    const float* __restrict__ sx, const float* __restrict__ sw,
    const float* __restrict__ bias, float* __restrict__ C) {
  __shared__ i8 As[2 * BUFSZ];          // 32 KB (double-buffered)
  __shared__ i8 Bs[2 * BUFSZ];          // 32 KB (double-buffered; reused
                                        //        as 32KB exchange buffer)
  const int tid  = threadIdx.x;
  const int lane = tid & 63;
  const int wave = tid >> 6;       // 0..7
  const int quad = lane >> 4;      // 0..3
  const int l16  = lane & 15;
  const int ot   = wave >> 1;      // 0..3: output 64x64 tile
  const int kgrp = wave & 1;       // 0..1: K-half of each group
  const int wm   = ot >> 1;        // 0..1 -> 64-row slab
  const int wn   = ot & 1;         // 0..1 -> 64-col slab
  const int bm = blockIdx.y;
  const int bn = blockIdx.x;

  const int rowA0 = bm * BM;
  const int rowB0 = bn * BN;

  // Staging: 1024 16B-chunks per matrix, 2 per thread (512 thr).
  // Global chunk-col pre-swizzled (involution c ^= row&7); LDS linear.
  const i8* srcA[2]; const i8* srcB[2];
  i8* dstA[2]; i8* dstB[2];
#pragma unroll
  for (int i = 0; i < 2; ++i) {
    int chunk = i * 512 + tid;              // 0..1023
    int row = chunk >> 3;                   // 0..127
    int csw = (chunk & 7) ^ (row & 7);
    srcA[i] = Aq + (size_t)(rowA0 + row) * K_IN + (csw << 4);
    srcB[i] = Bq + (size_t)(rowB0 + row) * K_IN + (csw << 4);
    dstA[i] = As + (size_t)(i * 512 + wave * 64) * 16;
    dstB[i] = Bs + (size_t)(i * 512 + wave * 64) * 16;
  }

  auto stage = [&](int buf, int t) {        // 4 global_load_lds / thread
    const size_t ko = (size_t)t * BK;
#pragma unroll
    for (int i = 0; i < 2; ++i)
      __builtin_amdgcn_global_load_lds(
          (const AS1 void*)(srcA[i] + ko),
          (AS3 void*)(dstA[i] + (size_t)buf * BUFSZ), 16, 0, 0);
#pragma unroll
    for (int i = 0; i < 2; ++i)
      __builtin_amdgcn_global_load_lds(
          (const AS1 void*)(srcB[i] + ko),
          (AS3 void*)(dstB[i] + (size_t)buf * BUFSZ), 16, 0, 0);
  };

  // s_w pointer for this wave's 4 column frags.
  const float* swp = sw + rowB0 + wn * 64 + l16;

  // Prologue: tile-0 stage; one-time full drain.
  stage(0, 0);
  __syncthreads();

  floatx4 master[4][4];
#pragma unroll
  for (int i = 0; i < 4; ++i)
#pragma unroll
    for (int j = 0; j < 4; ++j) master[i][j] = (floatx4)0.0f;

  const intx4 MAGICV = {0x4B400000, 0x4B400000, 0x4B400000, 0x4B400000};
  const float MAGICF = 12582912.0f;        // 1.5 * 2^23

  // This wave's k-half chunk: global chunk (4*kgrp + quad), swizzled by l16&7.
  const int xk = (((quad ^ (l16 & 7)) ^ (kgrp << 2)) << 4);

  for (int t = 0; t < NT; ++t) {
    const int cur = t & 1;
    // s_w(t) loads FIRST (oldest outstanding -> compiler waits vmcnt(4)
    // before the rescale, leaving stage(t+1) in flight).
    float swv[4];
#pragma unroll
    for (int j = 0; j < 4; ++j)
      swv[j] = swp[(size_t)t * N_OUT + j * 16];
    if (t + 1 < NT) {
      stage(cur ^ 1, t + 1);               // 4 loads in flight
      // outstanding: 4 (stage t) + 4 (swv t) + 4 (stage t+1) = 12
      asm volatile("s_waitcnt vmcnt(8)" ::: "memory");   // tile t landed
    } else {
      // outstanding: 4 (stage t) + 4 (swv t) = 8 -> drain stage(t) only
      asm volatile("s_waitcnt vmcnt(4)" ::: "memory");
    }
    __builtin_amdgcn_s_barrier();          // BARRIER_A: cur readable

    const i8* Ab = As + (size_t)cur * BUFSZ;
    const i8* Bb = Bs + (size_t)cur * BUFSZ;
    intx4 a[4], b[4];
#pragma unroll
    for (int i = 0; i < 4; ++i)
      a[i] = *(const intx4*)(Ab + (size_t)(wm * 64 + i * 16 + l16) * BK + xk);
#pragma unroll
    for (int j = 0; j < 4; ++j)
      b[j] = *(const intx4*)(Bb + (size_t)(wn * 64 + j * 16 + l16) * BK + xk);

    // 16 independent MFMAs (this wave's K=64 half of the group),
    // magic-seeded so int->float is a free bitcast; rescale by s_w[g,col]
    // applies linearly to half-group partials.
#pragma unroll
    for (int i = 0; i < 4; ++i)
#pragma unroll
      for (int j = 0; j < 4; ++j) {
        intx4 acc = __builtin_amdgcn_mfma_i32_16x16x64_i8(a[i], b[j], MAGICV, 0, 0, 0);
        master[i][j] += (__builtin_bit_cast(floatx4, acc) - MAGICF) * swv[j];
      }

    asm volatile("s_waitcnt lgkmcnt(0)" ::: "memory");
    __builtin_amdgcn_s_barrier();          // BARRIER_B: other buf writable
  }

  // ---- K-split pair reduction via Bs (32KB), 2 rounds, XOR-swizzled.
  // ALL master indices are literal (rule #20: no runtime indexing).
  floatx4* xb = (floatx4*)Bs;
  const int xbase = (ot * 64 + lane) * 8;
  if (kgrp == 1) {
#pragma unroll
    for (int ii = 0; ii < 2; ++ii)
#pragma unroll
      for (int j = 0; j < 4; ++j)
        xb[xbase + ((ii * 4 + j) ^ (lane & 7))] = master[ii][j];
  }
  __syncthreads();
  if (kgrp == 0) {
#pragma unroll
    for (int ii = 0; ii < 2; ++ii)
#pragma unroll
      for (int j = 0; j < 4; ++j)
        master[ii][j] += xb[xbase + ((ii * 4 + j) ^ (lane & 7))];
  }
  __syncthreads();
  if (kgrp == 0) {
#pragma unroll
    for (int ii = 2; ii < 4; ++ii)
#pragma unroll
      for (int j = 0; j < 4; ++j)
        xb[xbase + (((ii - 2) * 4 + j) ^ (lane & 7))] = master[ii][j];
  }
  __syncthreads();
  if (kgrp == 1) {
#pragma unroll
    for (int ii = 2; ii < 4; ++ii)
#pragma unroll
      for (int j = 0; j < 4; ++j)
        master[ii][j] += xb[xbase + (((ii - 2) * 4 + j) ^ (lane & 7))];
  }

  // Epilogue: kgrp0 owns rows i=0,1 (tile rows 0..31); kgrp1 owns i=2,3.
  // Static branches, literal master indices. C/D layout: col = lane&15,
  // row = quad*4 + reg.
#define STORE_ROW(i)                                                          \
  {                                                                           \
    float4 sxv = *(const float4*)(sx + rowA0 + wm * 64 + (i) * 16 + quad * 4);\
    _Pragma("unroll")                                                         \
    for (int j = 0; j < 4; ++j) {                                             \
      int col = rowB0 + wn * 64 + j * 16 + l16;                               \
      float bv = bias[col];                                                   \
      int rloc = wm * 64 + (i) * 16 + quad * 4;                               \
      C[(size_t)(rowA0 + rloc + 0) * N_OUT + col] = master[i][j][0] * sxv.x + bv; \
      C[(size_t)(rowA0 + rloc + 1) * N_OUT + col] = master[i][j][1] * sxv.y + bv; \
      C[(size_t)(rowA0 + rloc + 2) * N_OUT + col] = master[i][j][2] * sxv.z + bv; \
      C[(size_t)(rowA0 + rloc + 3) * N_OUT + col] = master[i][j][3] * sxv.w + bv; \
    }                                                                         \
  }

  if (kgrp == 0) { STORE_ROW(0); STORE_ROW(1); }
  else           { STORE_ROW(2); STORE_ROW(3); }
#undef STORE_ROW
}

extern "C" void kernel_launch(void* const* d_in, const int* in_sizes, int n_in,
                              void* d_out, int out_size, void* d_ws, size_t ws_size,
                              hipStream_t stream) {
  const float* x    = (const float*)d_in[0];
  const int*   wq   = (const int*)d_in[1];     // integer input -> int32 per harness
  const float* sw   = (const float*)d_in[2];
  const float* bias = (const float*)d_in[3];
  float* out = (float*)d_out;

  i8*    xq  = (i8*)d_ws;                                          // 8 MB
  i8*    wq8 = (i8*)((char*)d_ws + (size_t)M_TOK * K_IN);          // 16 MB
  float* sx  = (float*)((char*)d_ws + (size_t)M_TOK * K_IN
                                     + (size_t)N_OUT * K_IN);      // 8 KB

  {
    int nblocks = XQ_BLOCKS + WQ_BLOCKS;        // 6144
    quant_kernel<<<nblocks, 256, 0, stream>>>(x, wq, xq, wq8, sx);
  }
  {
    dim3 grid(N_OUT / BN, M_TOK / BM);          // (32, 16) = 512 blocks
    gemm_i8_kernel<<<grid, 512, 0, stream>>>(xq, wq8, sx, sw, bias, out);
  }
}